// Round 3
// baseline (854.092 us; speedup 1.0000x reference)
//
#include <hip/hip_runtime.h>
#include <hip/hip_fp16.h>

typedef _Float16 f16;
typedef _Float16 f16x4 __attribute__((ext_vector_type(4)));
typedef _Float16 f16x8 __attribute__((ext_vector_type(8)));
typedef float f32x4 __attribute__((ext_vector_type(4)));

#define MFMA16(a, b, c) __builtin_amdgcn_mfma_f32_16x16x32_f16((a), (b), (c), 0, 0, 0)

#define FLAG_CAP (1024 * 1024)
#define FLAG_TOL 1e-3f

// ---------------- scale computation ----------------

__global__ void k_zero(float* p, int* cnt) {
    if (threadIdx.x < 3) p[threadIdx.x] = 0.f;
    if (threadIdx.x == 3) { cnt[0] = 0; cnt[1] = 0; }
}

__global__ void k_absmax(const float* __restrict__ w, int n, float* __restrict__ out) {
    float m = 0.f;
    int stride = gridDim.x * blockDim.x;
    for (int i = blockIdx.x * blockDim.x + threadIdx.x; i < n; i += stride)
        m = fmaxf(m, fabsf(w[i]));
    #pragma unroll
    for (int o = 32; o > 0; o >>= 1) m = fmaxf(m, __shfl_down(m, o));
    __shared__ float sm[4];
    int lane = threadIdx.x & 63, wv = threadIdx.x >> 6;
    if (lane == 0) sm[wv] = m;
    __syncthreads();
    if (threadIdx.x == 0) {
        float mm = fmaxf(fmaxf(sm[0], sm[1]), fmaxf(sm[2], sm[3]));
        atomicMax((unsigned int*)out, __float_as_uint(mm));  // nonneg floats: uint max == float max
    }
}

// Replicate numpy-2.x fp32 semantics exactly:
//   s = fp32(fp32(max/7) + fp32(1e-8)); q = clip(rintf(w/s), -7, 7)  [all fp32]
// Store q as f16 (exact small int) AND the fp32 dequantized weight fp32(q*s)
// (the exact array the reference's sgemm consumes).
__global__ void k_quantw(const float* __restrict__ w, const float* __restrict__ wmax,
                         f16* __restrict__ q, float* __restrict__ wdq, int n) {
    float s = wmax[0] / 7.0f + 1e-8f;
    int i = blockIdx.x * blockDim.x + threadIdx.x;
    if (i < n) {
        float v = rintf(w[i] / s);           // rint = half-to-even, matches np.round
        v = fminf(fmaxf(v, -7.f), 7.f);
        q[i] = (f16)v;
        if (wdq) wdq[i] = v * s;             // fp32 single-rounding, == reference dequant
    }
}

// W3: 10x512 quantized, padded with zeros to 16x512 (no dequant array needed)
__global__ void k_quantw3(const float* __restrict__ w, const float* __restrict__ wmax,
                          f16* __restrict__ q) {
    float s = wmax[0] / 7.0f + 1e-8f;
    int i = blockIdx.x * blockDim.x + threadIdx.x;
    if (i < 16 * 512) {
        float v = 0.f;
        if (i < 10 * 512) {
            v = rintf(w[i] / s);
            v = fminf(fmaxf(v, -7.f), 7.f);
        }
        q[i] = (f16)v;
    }
}

// ---------------- GEMM1: [65536,784]f32 @ [512,784]^T int4w, fused relu-quant ----------------
// x split into two fp16 chunks -> ~fp32-exact products; epilogue emits integer
// codes 0..15 and FLAGS boundary-suspect outputs for exact BLAS-replicating fixup.

__global__ __launch_bounds__(256) void k_gemm1(
    const float* __restrict__ X, const f16* __restrict__ Q1,
    const float* __restrict__ wmax, const float* __restrict__ s1p,
    f16* __restrict__ A1, int* __restrict__ flagCnt, unsigned* __restrict__ flagList)
{
    __shared__ __align__(16) f16 As0[128][72];   // hi chunk, +8 pad
    __shared__ __align__(16) f16 As1[128][72];   // lo chunk
    __shared__ __align__(16) f16 Bs[128][72];

    const int t = threadIdx.x;
    const int row0 = blockIdx.y * 128;
    const int n0 = blockIdx.x * 128;
    const int lane = t & 63, wv = t >> 6;
    const int wr = wv >> 1, wc = wv & 1;

    f32x4 acc[4][4];
    #pragma unroll
    for (int m = 0; m < 4; ++m)
        #pragma unroll
        for (int n = 0; n < 4; ++n)
            acc[m][n] = (f32x4){0.f, 0.f, 0.f, 0.f};

    for (int k0 = 0; k0 < 784; k0 += 64) {
        #pragma unroll
        for (int i = 0; i < 8; ++i) {
            int f = t + 256 * i;
            int r = f >> 4, c = f & 15;
            int gk = k0 + c * 4;
            float4 v = make_float4(0.f, 0.f, 0.f, 0.f);
            if (gk < 784)
                v = *reinterpret_cast<const float4*>(X + (size_t)(row0 + r) * 784 + gk);
            float vv[4] = {v.x, v.y, v.z, v.w};
            f16x4 h0, h1;
            #pragma unroll
            for (int j = 0; j < 4; ++j) {
                f16 c0 = (f16)vv[j];                 // RNE
                float rr = vv[j] - (float)c0;        // exact residual
                h0[j] = c0;
                h1[j] = (f16)rr;
            }
            *reinterpret_cast<f16x4*>(&As0[r][c * 4]) = h0;
            *reinterpret_cast<f16x4*>(&As1[r][c * 4]) = h1;
        }
        #pragma unroll
        for (int i = 0; i < 4; ++i) {
            int f = t + 256 * i;
            int r = f >> 3, c = f & 7;
            int gk = k0 + c * 8;
            uint4 u = make_uint4(0u, 0u, 0u, 0u);
            if (gk < 784)
                u = *reinterpret_cast<const uint4*>(Q1 + (size_t)(n0 + r) * 784 + gk);
            *reinterpret_cast<uint4*>(&Bs[r][c * 8]) = u;
        }
        __syncthreads();

        #pragma unroll
        for (int kk = 0; kk < 2; ++kk) {
            int kb = kk * 32 + (lane >> 4) * 8;
            f16x8 bf[4], a0[4], a1f[4];
            #pragma unroll
            for (int n = 0; n < 4; ++n)
                bf[n] = *reinterpret_cast<const f16x8*>(&Bs[wc * 64 + n * 16 + (lane & 15)][kb]);
            #pragma unroll
            for (int m = 0; m < 4; ++m) {
                a0[m]  = *reinterpret_cast<const f16x8*>(&As0[wr * 64 + m * 16 + (lane & 15)][kb]);
                a1f[m] = *reinterpret_cast<const f16x8*>(&As1[wr * 64 + m * 16 + (lane & 15)][kb]);
            }
            #pragma unroll
            for (int m = 0; m < 4; ++m)
                #pragma unroll
                for (int n = 0; n < 4; ++n) {
                    acc[m][n] = MFMA16(a0[m],  bf[n], acc[m][n]);
                    acc[m][n] = MFMA16(a1f[m], bf[n], acc[m][n]);
                }
        }
        __syncthreads();
    }

    float sw = wmax[0] / 7.0f + 1e-8f;
    float s1v = s1p[0];
    #pragma unroll
    for (int m = 0; m < 4; ++m)
        #pragma unroll
        for (int n = 0; n < 4; ++n)
            #pragma unroll
            for (int j = 0; j < 4; ++j) {
                int row = row0 + wr * 64 + m * 16 + (lane >> 4) * 4 + j;
                int col = n0 + wc * 64 + n * 16 + (lane & 15);
                float h = sw * acc[m][n][j];
                float r = fmaxf(h, 0.f) / s1v;
                float qv = fminf(rintf(r), 15.f);
                A1[(size_t)row * 512 + col] = (f16)qv;
                float fr = r - floorf(r);
                if (fabsf(fr - 0.5f) < FLAG_TOL) {
                    int p = atomicAdd(flagCnt, 1);
                    if (p < FLAG_CAP) flagList[p] = (unsigned)(row * 512 + col);
                }
            }
}

// ---------------- fixup1: replicate reference sgemm bit-exactly for flagged elems --------
// One THREAD per element: sequential fp32 FMA over k ascending with the fp32
// dequantized weights — identical to BLAS GEBP accumulation order.

__global__ void k_fixup1(const float* __restrict__ X, const float* __restrict__ W1dq,
                         const float* __restrict__ s1p,
                         const int* __restrict__ flagCnt, const unsigned* __restrict__ flagList,
                         f16* __restrict__ A1)
{
    int tid = blockIdx.x * blockDim.x + threadIdx.x;
    int nthr = gridDim.x * blockDim.x;
    int n = flagCnt[0];
    if (n > FLAG_CAP) n = FLAG_CAP;
    float s1 = s1p[0];
    for (int i = tid; i < n; i += nthr) {
        unsigned idx = flagList[i];
        int row = (int)(idx >> 9), col = (int)(idx & 511);
        const float* xr = X + (size_t)row * 784;
        const float* wr = W1dq + (size_t)col * 784;
        float acc = 0.f;
        for (int k = 0; k < 784; ++k)
            acc = fmaf(xr[k], wr[k], acc);       // k-ascending, single acc: BLAS order
        float t = fmaxf(acc, 0.f) / s1;
        float code = fminf(rintf(t), 15.f);
        A1[(size_t)row * 512 + col] = (f16)code;
    }
}

// ---------------- GEMM2: integer-exact dot; flag boundary-suspect outputs ----------------

__global__ __launch_bounds__(256) void k_gemm2(
    const f16* __restrict__ A1, const f16* __restrict__ Q2,
    const float* __restrict__ wmax, const float* __restrict__ s1p, const float* __restrict__ s2p,
    f16* __restrict__ A2, int* __restrict__ flagCnt, unsigned* __restrict__ flagList)
{
    __shared__ __align__(16) f16 As[128][72];
    __shared__ __align__(16) f16 Bs[128][72];

    const int t = threadIdx.x;
    const int row0 = blockIdx.y * 128;
    const int n0 = blockIdx.x * 128;
    const int lane = t & 63, wv = t >> 6;
    const int wr = wv >> 1, wc = wv & 1;

    f32x4 acc[4][4];
    #pragma unroll
    for (int m = 0; m < 4; ++m)
        #pragma unroll
        for (int n = 0; n < 4; ++n)
            acc[m][n] = (f32x4){0.f, 0.f, 0.f, 0.f};

    for (int k0 = 0; k0 < 512; k0 += 64) {
        #pragma unroll
        for (int i = 0; i < 4; ++i) {
            int f = t + 256 * i;
            int r = f >> 3, c = f & 7;
            *reinterpret_cast<uint4*>(&As[r][c * 8]) =
                *reinterpret_cast<const uint4*>(A1 + (size_t)(row0 + r) * 512 + k0 + c * 8);
        }
        #pragma unroll
        for (int i = 0; i < 4; ++i) {
            int f = t + 256 * i;
            int r = f >> 3, c = f & 7;
            *reinterpret_cast<uint4*>(&Bs[r][c * 8]) =
                *reinterpret_cast<const uint4*>(Q2 + (size_t)(n0 + r) * 512 + k0 + c * 8);
        }
        __syncthreads();

        #pragma unroll
        for (int kk = 0; kk < 2; ++kk) {
            int kb = kk * 32 + (lane >> 4) * 8;
            f16x8 bf[4], af[4];
            #pragma unroll
            for (int n = 0; n < 4; ++n)
                bf[n] = *reinterpret_cast<const f16x8*>(&Bs[wc * 64 + n * 16 + (lane & 15)][kb]);
            #pragma unroll
            for (int m = 0; m < 4; ++m)
                af[m] = *reinterpret_cast<const f16x8*>(&As[wr * 64 + m * 16 + (lane & 15)][kb]);
            #pragma unroll
            for (int m = 0; m < 4; ++m)
                #pragma unroll
                for (int n = 0; n < 4; ++n)
                    acc[m][n] = MFMA16(af[m], bf[n], acc[m][n]);
        }
        __syncthreads();
    }

    // exact integer N2; compute code-space value in fp64 only to measure
    // distance to the rounding boundary (ref's own value differs by <=~3e-6)
    double cs = (double)s1p[0] * (double)(wmax[0] / 7.0f + 1e-8f);
    double s2v = (double)s2p[0];
    #pragma unroll
    for (int m = 0; m < 4; ++m)
        #pragma unroll
        for (int n = 0; n < 4; ++n)
            #pragma unroll
            for (int j = 0; j < 4; ++j) {
                int row = row0 + wr * 64 + m * 16 + (lane >> 4) * 4 + j;
                int col = n0 + wc * 64 + n * 16 + (lane & 15);
                double r = fmax((double)acc[m][n][j] * cs, 0.0) / s2v;
                double qv = fmin(rint(r), 15.0);
                A2[(size_t)row * 512 + col] = (f16)qv;
                double fr = r - floor(r);
                if (fabs(fr - 0.5) < (double)FLAG_TOL && r < 16.0) {
                    int p = atomicAdd(flagCnt, 1);
                    if (p < FLAG_CAP) flagList[p] = (unsigned)(row * 512 + col);
                }
            }
}

// ---------------- fixup2: BLAS-replicating sequential fp32 FMA for flagged h2 ----------

__global__ void k_fixup2(const f16* __restrict__ A1, const float* __restrict__ W2dq,
                         const float* __restrict__ s1p, const float* __restrict__ s2p,
                         const int* __restrict__ flagCnt, const unsigned* __restrict__ flagList,
                         f16* __restrict__ A2)
{
    int tid = blockIdx.x * blockDim.x + threadIdx.x;
    int nthr = gridDim.x * blockDim.x;
    int n = flagCnt[0];
    if (n > FLAG_CAP) n = FLAG_CAP;
    float s1 = s1p[0], s2 = s2p[0];
    for (int i = tid; i < n; i += nthr) {
        unsigned idx = flagList[i];
        int row = (int)(idx >> 9), col = (int)(idx & 511);
        const f16* ar = A1 + (size_t)row * 512;
        const float* wr = W2dq + (size_t)col * 512;
        float acc = 0.f;
        for (int k = 0; k < 512; ++k) {
            float adq = (float)ar[k] * s1;           // fp32 dequant, == ref
            acc = fmaf(adq, wr[k], acc);             // k-ascending, single acc
        }
        float t = fmaxf(acc, 0.f) / s2;
        float code = fminf(rintf(t), 15.f);
        A2[(size_t)row * 512 + col] = (f16)code;
    }
}

// ---------------- GEMM3: integer-exact dot -> fp32 logits ----------------

__global__ __launch_bounds__(256) void k_gemm3(
    const f16* __restrict__ A2, const f16* __restrict__ Q3,
    const float* __restrict__ wmax, const float* __restrict__ s2p,
    float* __restrict__ Out)
{
    __shared__ __align__(16) f16 As[256][72];
    __shared__ __align__(16) f16 Bs[16][72];

    const int t = threadIdx.x;
    const int row0 = blockIdx.x * 256;
    const int lane = t & 63, wv = t >> 6;

    f32x4 acc[4];
    #pragma unroll
    for (int m = 0; m < 4; ++m) acc[m] = (f32x4){0.f, 0.f, 0.f, 0.f};

    for (int k0 = 0; k0 < 512; k0 += 64) {
        #pragma unroll
        for (int i = 0; i < 8; ++i) {
            int f = t + 256 * i;
            int r = f >> 3, c = f & 7;
            *reinterpret_cast<uint4*>(&As[r][c * 8]) =
                *reinterpret_cast<const uint4*>(A2 + (size_t)(row0 + r) * 512 + k0 + c * 8);
        }
        if (t < 128) {
            int r = t >> 3, c = t & 7;
            *reinterpret_cast<uint4*>(&Bs[r][c * 8]) =
                *reinterpret_cast<const uint4*>(Q3 + (size_t)r * 512 + k0 + c * 8);
        }
        __syncthreads();

        #pragma unroll
        for (int kk = 0; kk < 2; ++kk) {
            int kb = kk * 32 + (lane >> 4) * 8;
            f16x8 bf = *reinterpret_cast<const f16x8*>(&Bs[lane & 15][kb]);
            #pragma unroll
            for (int m = 0; m < 4; ++m) {
                f16x8 af = *reinterpret_cast<const f16x8*>(&As[wv * 64 + m * 16 + (lane & 15)][kb]);
                acc[m] = MFMA16(af, bf, acc[m]);
            }
        }
        __syncthreads();
    }

    double cs = (double)s2p[0] * (double)(wmax[0] / 7.0f + 1e-8f);
    #pragma unroll
    for (int m = 0; m < 4; ++m)
        #pragma unroll
        for (int j = 0; j < 4; ++j) {
            int row = row0 + wv * 64 + m * 16 + (lane >> 4) * 4 + j;
            int col = lane & 15;
            if (col < 10)
                Out[(size_t)row * 10 + col] = (float)((double)acc[m][j] * cs);
        }
}

// ---------------- launch ----------------

extern "C" void kernel_launch(void* const* d_in, const int* in_sizes, int n_in,
                              void* d_out, int out_size, void* d_ws, size_t ws_size,
                              hipStream_t stream)
{
    (void)in_sizes; (void)n_in; (void)out_size; (void)ws_size;

    const float* X  = (const float*)d_in[0];
    const float* W1 = (const float*)d_in[1];
    const float* W2 = (const float*)d_in[2];
    const float* W3 = (const float*)d_in[3];
    const float* s1 = (const float*)d_in[4];
    const float* s2 = (const float*)d_in[5];
    float* Out = (float*)d_out;

    char* ws = (char*)d_ws;
    float* maxes   = (float*)ws;                          // 12 B
    int*   cnts    = (int*)(ws + 16);                     // 2 ints (cnt1, cnt2)
    f16*   q1      = (f16*)(ws + 256);                    // 802816 B
    f16*   q2      = (f16*)(ws + 256 + 802816);           // 524288 B
    f16*   q3      = (f16*)(ws + 256 + 802816 + 524288);  // 16384 B
    float* w1dq    = (float*)(ws + (size_t)(2u << 20));               // 1605632 B
    float* w2dq    = (float*)(ws + (size_t)(2u << 20) + 1605632);     // 1048576 B
    f16*   a1      = (f16*)(ws + (size_t)(8u << 20));                 // 64 MB
    f16*   a2      = (f16*)(ws + (size_t)(8u << 20) + (size_t)(64u << 20));   // 64 MB
    unsigned* fl1  = (unsigned*)(ws + (size_t)(136u << 20));          // 4 MB
    unsigned* fl2  = (unsigned*)(ws + (size_t)(140u << 20));          // 4 MB

    k_zero<<<1, 64, 0, stream>>>(maxes, cnts);
    k_absmax<<<256, 256, 0, stream>>>(W1, 512 * 784, maxes + 0);
    k_absmax<<<256, 256, 0, stream>>>(W2, 512 * 512, maxes + 1);
    k_absmax<<<8, 256, 0, stream>>>(W3, 10 * 512, maxes + 2);
    k_quantw<<<(512 * 784 + 255) / 256, 256, 0, stream>>>(W1, maxes + 0, q1, w1dq, 512 * 784);
    k_quantw<<<(512 * 512 + 255) / 256, 256, 0, stream>>>(W2, maxes + 1, q2, w2dq, 512 * 512);
    k_quantw3<<<(16 * 512 + 255) / 256, 256, 0, stream>>>(W3, maxes + 2, q3);

    k_gemm1<<<dim3(4, 512), 256, 0, stream>>>(X, q1, maxes + 0, s1, a1, cnts + 0, fl1);
    k_fixup1<<<512, 256, 0, stream>>>(X, w1dq, s1, cnts + 0, fl1, a1);
    k_gemm2<<<dim3(4, 512), 256, 0, stream>>>(a1, q2, maxes + 1, s1, s2, a2, cnts + 1, fl2);
    k_fixup2<<<512, 256, 0, stream>>>(a1, w2dq, s1, s2, cnts + 1, fl2, a2);
    k_gemm3<<<256, 256, 0, stream>>>(a2, q3, maxes + 2, s2, Out);
}

// Round 4
// 802.142 us; speedup vs baseline: 1.0648x; 1.0648x over previous
//
#include <hip/hip_runtime.h>
#include <hip/hip_fp16.h>

typedef _Float16 f16;
typedef _Float16 f16x4 __attribute__((ext_vector_type(4)));
typedef _Float16 f16x8 __attribute__((ext_vector_type(8)));
typedef float f32x4 __attribute__((ext_vector_type(4)));

#define MFMA16(a, b, c) __builtin_amdgcn_mfma_f32_16x16x32_f16((a), (b), (c), 0, 0, 0)

#define FLAG_CAP (1024 * 1024)
#define FLAG_TOL 1e-3f

// async global->LDS, 16 B per lane. LDS dest is wave-uniform base; HW writes
// base + laneid*16. Global src is per-lane.
__device__ __forceinline__ void gld16(const f16* g, f16* l) {
    __builtin_amdgcn_global_load_lds(
        (const __attribute__((address_space(1))) unsigned int*)g,
        (__attribute__((address_space(3))) unsigned int*)l,
        16, 0, 0);
}

// ---------------- scale computation ----------------

__global__ void k_zero(float* p, int* cnt) {
    if (threadIdx.x < 3) p[threadIdx.x] = 0.f;
    if (threadIdx.x == 3) { cnt[0] = 0; cnt[1] = 0; }
}

__global__ void k_absmax(const float* __restrict__ w, int n, float* __restrict__ out) {
    float m = 0.f;
    int stride = gridDim.x * blockDim.x;
    for (int i = blockIdx.x * blockDim.x + threadIdx.x; i < n; i += stride)
        m = fmaxf(m, fabsf(w[i]));
    #pragma unroll
    for (int o = 32; o > 0; o >>= 1) m = fmaxf(m, __shfl_down(m, o));
    __shared__ float sm[4];
    int lane = threadIdx.x & 63, wv = threadIdx.x >> 6;
    if (lane == 0) sm[wv] = m;
    __syncthreads();
    if (threadIdx.x == 0) {
        float mm = fmaxf(fmaxf(sm[0], sm[1]), fmaxf(sm[2], sm[3]));
        atomicMax((unsigned int*)out, __float_as_uint(mm));
    }
}

// W1 quant: compact q1 [512][784] (fallback path), fp32 dequant w1dq (fixup),
// and duplicated+padded B panel q1p [512][1664]: [q|0pad | q|0pad].
__global__ void k_quantw1p(const float* __restrict__ w, const float* __restrict__ wmax,
                           f16* __restrict__ q1, float* __restrict__ wdq,
                           f16* __restrict__ q1p) {
    int i = blockIdx.x * blockDim.x + threadIdx.x;
    if (i >= 512 * 832) return;
    int n = i / 832, k = i - n * 832;
    float v = 0.f;
    if (k < 784) {
        float s = wmax[0] / 7.0f + 1e-8f;
        v = rintf(w[n * 784 + k] / s);     // fp32 ops replicate numpy fp32 semantics
        v = fminf(fmaxf(v, -7.f), 7.f);
        q1[n * 784 + k] = (f16)v;
        wdq[n * 784 + k] = v * s;
    }
    q1p[(size_t)n * 1664 + k] = (f16)v;
    q1p[(size_t)n * 1664 + 832 + k] = (f16)v;
}

__global__ void k_quantw(const float* __restrict__ w, const float* __restrict__ wmax,
                         f16* __restrict__ q, float* __restrict__ wdq, int n) {
    float s = wmax[0] / 7.0f + 1e-8f;
    int i = blockIdx.x * blockDim.x + threadIdx.x;
    if (i < n) {
        float v = rintf(w[i] / s);
        v = fminf(fmaxf(v, -7.f), 7.f);
        q[i] = (f16)v;
        if (wdq) wdq[i] = v * s;
    }
}

__global__ void k_quantw3(const float* __restrict__ w, const float* __restrict__ wmax,
                          f16* __restrict__ q) {
    float s = wmax[0] / 7.0f + 1e-8f;
    int i = blockIdx.x * blockDim.x + threadIdx.x;
    if (i < 16 * 512) {
        float v = 0.f;
        if (i < 10 * 512) {
            v = rintf(w[i] / s);
            v = fminf(fmaxf(v, -7.f), 7.f);
        }
        q[i] = (f16)v;
    }
}

// ---------------- prep: split X fp32 -> [hi(832) | lo(832)] f16, zero-padded ----------------

__global__ void k_prep(const float* __restrict__ X, f16* __restrict__ Xs) {
    int row = blockIdx.x;
    int p = threadIdx.x;
    if (p >= 208) return;
    f16x4 h0 = (f16x4){0, 0, 0, 0}, h1 = (f16x4){0, 0, 0, 0};
    if (p < 196) {  // 196*4 = 784 exactly
        float4 v = *reinterpret_cast<const float4*>(X + (size_t)row * 784 + p * 4);
        float vv[4] = {v.x, v.y, v.z, v.w};
        #pragma unroll
        for (int j = 0; j < 4; ++j) {
            f16 c0 = (f16)vv[j];             // RNE
            h0[j] = c0;
            h1[j] = (f16)(vv[j] - (float)c0);  // exact residual
        }
    }
    *reinterpret_cast<f16x4*>(Xs + (size_t)row * 1664 + p * 4) = h0;
    *reinterpret_cast<f16x4*>(Xs + (size_t)row * 1664 + 832 + p * 4) = h1;
}

// ---------------- fast GEMM1: m97 structure, A=Xs[M][1664], B=q1p[512][1664] ----------------

__global__ __launch_bounds__(256) void k_gemm1f(
    const f16* __restrict__ A, const f16* __restrict__ B,
    const float* __restrict__ wmax, const float* __restrict__ s1p,
    f16* __restrict__ A1, int* __restrict__ flagCnt, unsigned* __restrict__ flagList)
{
    constexpr int KP = 1664;
    __shared__ __align__(16) f16 As[128 * 64];
    __shared__ __align__(16) f16 Bs[128 * 64];

    const int t = threadIdx.x;
    const int lane = t & 63, w = t >> 6;
    const int wr = w >> 1, wc = w & 1;
    const int row0 = blockIdx.y * 128;
    const int n0 = blockIdx.x * 128;

    f32x4 acc[4][4];
    #pragma unroll
    for (int m = 0; m < 4; ++m)
        #pragma unroll
        for (int n = 0; n < 4; ++n) acc[m][n] = (f32x4){0.f, 0.f, 0.f, 0.f};

    // per-lane global staging base: row lr within 8-row chunk, col lc
    const int lr = lane >> 3, lc = (lane & 7) * 8;
    const f16* Ab = A + (size_t)(row0 + lr) * KP + lc;
    const f16* Bb = B + (size_t)(n0 + lr) * KP + lc;

    for (int k0 = 0; k0 < KP; k0 += 64) {
        #pragma unroll
        for (int i = 0; i < 4; ++i) {
            int ch = w * 4 + i;   // 16 chunks x 8 rows = 128 rows
            gld16(Ab + (size_t)ch * 8 * KP + k0, &As[ch * 512]);
            gld16(Bb + (size_t)ch * 8 * KP + k0, &Bs[ch * 512]);
        }
        __syncthreads();   // compiler drains vmcnt before barrier

        #pragma unroll
        for (int kk = 0; kk < 2; ++kk) {
            int kb = kk * 32 + (lane >> 4) * 8;
            f16x8 bf[4], af[4];
            #pragma unroll
            for (int n = 0; n < 4; ++n)
                bf[n] = *reinterpret_cast<const f16x8*>(&Bs[(wc * 64 + n * 16 + (lane & 15)) * 64 + kb]);
            #pragma unroll
            for (int m = 0; m < 4; ++m)
                af[m] = *reinterpret_cast<const f16x8*>(&As[(wr * 64 + m * 16 + (lane & 15)) * 64 + kb]);
            #pragma unroll
            for (int m = 0; m < 4; ++m)
                #pragma unroll
                for (int n = 0; n < 4; ++n)
                    acc[m][n] = MFMA16(af[m], bf[n], acc[m][n]);
        }
        __syncthreads();
    }

    float sw = wmax[0] / 7.0f + 1e-8f;
    float s1v = s1p[0];
    #pragma unroll
    for (int m = 0; m < 4; ++m)
        #pragma unroll
        for (int n = 0; n < 4; ++n)
            #pragma unroll
            for (int j = 0; j < 4; ++j) {
                int row = row0 + wr * 64 + m * 16 + (lane >> 4) * 4 + j;
                int col = n0 + wc * 64 + n * 16 + (lane & 15);
                float h = sw * acc[m][n][j];
                float r = fmaxf(h, 0.f) / s1v;
                float qv = fminf(rintf(r), 15.f);
                A1[(size_t)row * 512 + col] = (f16)qv;
                float fr = r - floorf(r);
                if (fabsf(fr - 0.5f) < FLAG_TOL) {
                    int p = atomicAdd(flagCnt, 1);
                    if (p < FLAG_CAP) flagList[p] = (unsigned)(row * 512 + col);
                }
            }
}

// ---------------- fallback GEMM1 (round-3, in-kernel split) ----------------

__global__ __launch_bounds__(256) void k_gemm1s(
    const float* __restrict__ X, const f16* __restrict__ Q1,
    const float* __restrict__ wmax, const float* __restrict__ s1p,
    f16* __restrict__ A1, int* __restrict__ flagCnt, unsigned* __restrict__ flagList)
{
    __shared__ __align__(16) f16 As0[128][72];
    __shared__ __align__(16) f16 As1[128][72];
    __shared__ __align__(16) f16 Bs[128][72];

    const int t = threadIdx.x;
    const int row0 = blockIdx.y * 128;
    const int n0 = blockIdx.x * 128;
    const int lane = t & 63, wv = t >> 6;
    const int wr = wv >> 1, wc = wv & 1;

    f32x4 acc[4][4];
    #pragma unroll
    for (int m = 0; m < 4; ++m)
        #pragma unroll
        for (int n = 0; n < 4; ++n) acc[m][n] = (f32x4){0.f, 0.f, 0.f, 0.f};

    for (int k0 = 0; k0 < 784; k0 += 64) {
        #pragma unroll
        for (int i = 0; i < 8; ++i) {
            int f = t + 256 * i;
            int r = f >> 4, c = f & 15;
            int gk = k0 + c * 4;
            float4 v = make_float4(0.f, 0.f, 0.f, 0.f);
            if (gk < 784)
                v = *reinterpret_cast<const float4*>(X + (size_t)(row0 + r) * 784 + gk);
            float vv[4] = {v.x, v.y, v.z, v.w};
            f16x4 h0, h1;
            #pragma unroll
            for (int j = 0; j < 4; ++j) {
                f16 c0 = (f16)vv[j];
                h0[j] = c0;
                h1[j] = (f16)(vv[j] - (float)c0);
            }
            *reinterpret_cast<f16x4*>(&As0[r][c * 4]) = h0;
            *reinterpret_cast<f16x4*>(&As1[r][c * 4]) = h1;
        }
        #pragma unroll
        for (int i = 0; i < 4; ++i) {
            int f = t + 256 * i;
            int r = f >> 3, c = f & 7;
            int gk = k0 + c * 8;
            uint4 u = make_uint4(0u, 0u, 0u, 0u);
            if (gk < 784)
                u = *reinterpret_cast<const uint4*>(Q1 + (size_t)(n0 + r) * 784 + gk);
            *reinterpret_cast<uint4*>(&Bs[r][c * 8]) = u;
        }
        __syncthreads();

        #pragma unroll
        for (int kk = 0; kk < 2; ++kk) {
            int kb = kk * 32 + (lane >> 4) * 8;
            f16x8 bf[4], a0[4], a1f[4];
            #pragma unroll
            for (int n = 0; n < 4; ++n)
                bf[n] = *reinterpret_cast<const f16x8*>(&Bs[wc * 64 + n * 16 + (lane & 15)][kb]);
            #pragma unroll
            for (int m = 0; m < 4; ++m) {
                a0[m]  = *reinterpret_cast<const f16x8*>(&As0[wr * 64 + m * 16 + (lane & 15)][kb]);
                a1f[m] = *reinterpret_cast<const f16x8*>(&As1[wr * 64 + m * 16 + (lane & 15)][kb]);
            }
            #pragma unroll
            for (int m = 0; m < 4; ++m)
                #pragma unroll
                for (int n = 0; n < 4; ++n) {
                    acc[m][n] = MFMA16(a0[m],  bf[n], acc[m][n]);
                    acc[m][n] = MFMA16(a1f[m], bf[n], acc[m][n]);
                }
        }
        __syncthreads();
    }

    float sw = wmax[0] / 7.0f + 1e-8f;
    float s1v = s1p[0];
    #pragma unroll
    for (int m = 0; m < 4; ++m)
        #pragma unroll
        for (int n = 0; n < 4; ++n)
            #pragma unroll
            for (int j = 0; j < 4; ++j) {
                int row = row0 + wr * 64 + m * 16 + (lane >> 4) * 4 + j;
                int col = n0 + wc * 64 + n * 16 + (lane & 15);
                float h = sw * acc[m][n][j];
                float r = fmaxf(h, 0.f) / s1v;
                float qv = fminf(rintf(r), 15.f);
                A1[(size_t)row * 512 + col] = (f16)qv;
                float fr = r - floorf(r);
                if (fabsf(fr - 0.5f) < FLAG_TOL) {
                    int p = atomicAdd(flagCnt, 1);
                    if (p < FLAG_CAP) flagList[p] = (unsigned)(row * 512 + col);
                }
            }
}

// ---------------- fixup1: BLAS-replicating sequential fp32 FMA ----------------

__global__ void k_fixup1(const float* __restrict__ X, const float* __restrict__ W1dq,
                         const float* __restrict__ s1p,
                         const int* __restrict__ flagCnt, const unsigned* __restrict__ flagList,
                         f16* __restrict__ A1)
{
    int tid = blockIdx.x * blockDim.x + threadIdx.x;
    int nthr = gridDim.x * blockDim.x;
    int n = flagCnt[0];
    if (n > FLAG_CAP) n = FLAG_CAP;
    float s1 = s1p[0];
    for (int i = tid; i < n; i += nthr) {
        unsigned idx = flagList[i];
        int row = (int)(idx >> 9), col = (int)(idx & 511);
        const float* xr = X + (size_t)row * 784;
        const float* wr = W1dq + (size_t)col * 784;
        float acc = 0.f;
        for (int k = 0; k < 784; ++k)
            acc = fmaf(xr[k], wr[k], acc);
        float tq = fmaxf(acc, 0.f) / s1;
        float code = fminf(rintf(tq), 15.f);
        A1[(size_t)row * 512 + col] = (f16)code;
    }
}

// ---------------- fast GEMM2: m97 structure, exact integer dot, fp64 epilogue ----------------

__global__ __launch_bounds__(256) void k_gemm2f(
    const f16* __restrict__ A, const f16* __restrict__ B,
    const float* __restrict__ wmax, const float* __restrict__ s1p, const float* __restrict__ s2p,
    f16* __restrict__ A2, int* __restrict__ flagCnt, unsigned* __restrict__ flagList)
{
    constexpr int KP = 512;
    __shared__ __align__(16) f16 As[128 * 64];
    __shared__ __align__(16) f16 Bs[128 * 64];

    const int t = threadIdx.x;
    const int lane = t & 63, w = t >> 6;
    const int wr = w >> 1, wc = w & 1;
    const int row0 = blockIdx.y * 128;
    const int n0 = blockIdx.x * 128;

    f32x4 acc[4][4];
    #pragma unroll
    for (int m = 0; m < 4; ++m)
        #pragma unroll
        for (int n = 0; n < 4; ++n) acc[m][n] = (f32x4){0.f, 0.f, 0.f, 0.f};

    const int lr = lane >> 3, lc = (lane & 7) * 8;
    const f16* Ab = A + (size_t)(row0 + lr) * KP + lc;
    const f16* Bb = B + (size_t)(n0 + lr) * KP + lc;

    for (int k0 = 0; k0 < KP; k0 += 64) {
        #pragma unroll
        for (int i = 0; i < 4; ++i) {
            int ch = w * 4 + i;
            gld16(Ab + (size_t)ch * 8 * KP + k0, &As[ch * 512]);
            gld16(Bb + (size_t)ch * 8 * KP + k0, &Bs[ch * 512]);
        }
        __syncthreads();

        #pragma unroll
        for (int kk = 0; kk < 2; ++kk) {
            int kb = kk * 32 + (lane >> 4) * 8;
            f16x8 bf[4], af[4];
            #pragma unroll
            for (int n = 0; n < 4; ++n)
                bf[n] = *reinterpret_cast<const f16x8*>(&Bs[(wc * 64 + n * 16 + (lane & 15)) * 64 + kb]);
            #pragma unroll
            for (int m = 0; m < 4; ++m)
                af[m] = *reinterpret_cast<const f16x8*>(&As[(wr * 64 + m * 16 + (lane & 15)) * 64 + kb]);
            #pragma unroll
            for (int m = 0; m < 4; ++m)
                #pragma unroll
                for (int n = 0; n < 4; ++n)
                    acc[m][n] = MFMA16(af[m], bf[n], acc[m][n]);
        }
        __syncthreads();
    }

    double cs = (double)s1p[0] * (double)(wmax[0] / 7.0f + 1e-8f);
    double s2v = (double)s2p[0];
    #pragma unroll
    for (int m = 0; m < 4; ++m)
        #pragma unroll
        for (int n = 0; n < 4; ++n)
            #pragma unroll
            for (int j = 0; j < 4; ++j) {
                int row = row0 + wr * 64 + m * 16 + (lane >> 4) * 4 + j;
                int col = n0 + wc * 64 + n * 16 + (lane & 15);
                double r = fmax((double)acc[m][n][j] * cs, 0.0) / s2v;
                double qv = fmin(rint(r), 15.0);
                A2[(size_t)row * 512 + col] = (f16)qv;
                double fr = r - floor(r);
                if (fabs(fr - 0.5) < (double)FLAG_TOL && r < 16.0) {
                    int p = atomicAdd(flagCnt, 1);
                    if (p < FLAG_CAP) flagList[p] = (unsigned)(row * 512 + col);
                }
            }
}

// ---------------- fixup2 ----------------

__global__ void k_fixup2(const f16* __restrict__ A1, const float* __restrict__ W2dq,
                         const float* __restrict__ s1p, const float* __restrict__ s2p,
                         const int* __restrict__ flagCnt, const unsigned* __restrict__ flagList,
                         f16* __restrict__ A2)
{
    int tid = blockIdx.x * blockDim.x + threadIdx.x;
    int nthr = gridDim.x * blockDim.x;
    int n = flagCnt[0];
    if (n > FLAG_CAP) n = FLAG_CAP;
    float s1 = s1p[0], s2 = s2p[0];
    for (int i = tid; i < n; i += nthr) {
        unsigned idx = flagList[i];
        int row = (int)(idx >> 9), col = (int)(idx & 511);
        const f16* ar = A1 + (size_t)row * 512;
        const float* wr = W2dq + (size_t)col * 512;
        float acc = 0.f;
        for (int k = 0; k < 512; ++k) {
            float adq = (float)ar[k] * s1;
            acc = fmaf(adq, wr[k], acc);
        }
        float tq = fmaxf(acc, 0.f) / s2;
        float code = fminf(rintf(tq), 15.f);
        A2[(size_t)row * 512 + col] = (f16)code;
    }
}

// ---------------- GEMM3: [65536,512] @ [16,512]^T -> fp32 logits ----------------

__global__ __launch_bounds__(256) void k_gemm3(
    const f16* __restrict__ A2, const f16* __restrict__ Q3,
    const float* __restrict__ wmax, const float* __restrict__ s2p,
    float* __restrict__ Out)
{
    __shared__ __align__(16) f16 As[256][72];
    __shared__ __align__(16) f16 Bs[16][72];

    const int t = threadIdx.x;
    const int row0 = blockIdx.x * 256;
    const int lane = t & 63, wv = t >> 6;

    f32x4 acc[4];
    #pragma unroll
    for (int m = 0; m < 4; ++m) acc[m] = (f32x4){0.f, 0.f, 0.f, 0.f};

    for (int k0 = 0; k0 < 512; k0 += 64) {
        #pragma unroll
        for (int i = 0; i < 8; ++i) {
            int f = t + 256 * i;
            int r = f >> 3, c = f & 7;
            *reinterpret_cast<uint4*>(&As[r][c * 8]) =
                *reinterpret_cast<const uint4*>(A2 + (size_t)(row0 + r) * 512 + k0 + c * 8);
        }
        if (t < 128) {
            int r = t >> 3, c = t & 7;
            *reinterpret_cast<uint4*>(&Bs[r][c * 8]) =
                *reinterpret_cast<const uint4*>(Q3 + (size_t)r * 512 + k0 + c * 8);
        }
        __syncthreads();

        #pragma unroll
        for (int kk = 0; kk < 2; ++kk) {
            int kb = kk * 32 + (lane >> 4) * 8;
            f16x8 bf = *reinterpret_cast<const f16x8*>(&Bs[lane & 15][kb]);
            #pragma unroll
            for (int m = 0; m < 4; ++m) {
                f16x8 af = *reinterpret_cast<const f16x8*>(&As[wv * 64 + m * 16 + (lane & 15)][kb]);
                acc[m] = MFMA16(af, bf, acc[m]);
            }
        }
        __syncthreads();
    }

    double cs = (double)s2p[0] * (double)(wmax[0] / 7.0f + 1e-8f);
    #pragma unroll
    for (int m = 0; m < 4; ++m)
        #pragma unroll
        for (int j = 0; j < 4; ++j) {
            int row = row0 + wv * 64 + m * 16 + (lane >> 4) * 4 + j;
            int col = lane & 15;
            if (col < 10)
                Out[(size_t)row * 10 + col] = (float)((double)acc[m][j] * cs);
        }
}

// ---------------- launch ----------------

extern "C" void kernel_launch(void* const* d_in, const int* in_sizes, int n_in,
                              void* d_out, int out_size, void* d_ws, size_t ws_size,
                              hipStream_t stream)
{
    (void)in_sizes; (void)n_in; (void)out_size;

    const float* X  = (const float*)d_in[0];
    const float* W1 = (const float*)d_in[1];
    const float* W2 = (const float*)d_in[2];
    const float* W3 = (const float*)d_in[3];
    const float* s1 = (const float*)d_in[4];
    const float* s2 = (const float*)d_in[5];
    float* Out = (float*)d_out;

    char* ws = (char*)d_ws;
    float* maxes   = (float*)ws;
    int*   cnts    = (int*)(ws + 16);
    f16*   q1      = (f16*)(ws + 4096);                           // 802816 B
    f16*   q2      = (f16*)(ws + (size_t)(1u << 20));             // 524288 B
    f16*   q3      = (f16*)(ws + (size_t)(1u << 20) + 600000);    // 16384 B
    f16*   q1p     = (f16*)(ws + (size_t)(2u << 20));             // 1703936 B
    float* w1dq    = (float*)(ws + (size_t)(4u << 20));           // 1605632 B
    float* w2dq    = (float*)(ws + (size_t)(6u << 20));           // 1048576 B
    f16*   a1      = (f16*)(ws + (size_t)(8u << 20));             // 64 MB
    f16*   a2      = (f16*)(ws + (size_t)(72u << 20));            // 64 MB
    unsigned* fl1  = (unsigned*)(ws + (size_t)(136u << 20));      // 4 MB
    unsigned* fl2  = (unsigned*)(ws + (size_t)(140u << 20));      // 4 MB
    f16*   Xs      = (f16*)(ws + (size_t)(144u << 20));           // 218 MB (fast path)

    const bool big = ws_size >= ((size_t)356 << 20);

    k_zero<<<1, 64, 0, stream>>>(maxes, cnts);
    k_absmax<<<256, 256, 0, stream>>>(W1, 512 * 784, maxes + 0);
    k_absmax<<<256, 256, 0, stream>>>(W2, 512 * 512, maxes + 1);
    k_absmax<<<8, 256, 0, stream>>>(W3, 10 * 512, maxes + 2);
    k_quantw1p<<<(512 * 832 + 255) / 256, 256, 0, stream>>>(W1, maxes + 0, q1, w1dq, q1p);
    k_quantw<<<(512 * 512 + 255) / 256, 256, 0, stream>>>(W2, maxes + 1, q2, w2dq, 512 * 512);
    k_quantw3<<<(16 * 512 + 255) / 256, 256, 0, stream>>>(W3, maxes + 2, q3);

    if (big) {
        k_prep<<<65536, 256, 0, stream>>>(X, Xs);
        k_gemm1f<<<dim3(4, 512), 256, 0, stream>>>(Xs, q1p, maxes + 0, s1, a1, cnts + 0, fl1);
    } else {
        k_gemm1s<<<dim3(4, 512), 256, 0, stream>>>(X, q1, maxes + 0, s1, a1, cnts + 0, fl1);
    }
    k_fixup1<<<512, 256, 0, stream>>>(X, w1dq, s1, cnts + 0, fl1, a1);
    k_gemm2f<<<dim3(4, 512), 256, 0, stream>>>(a1, q2, maxes + 1, s1, s2, a2, cnts + 1, fl2);
    k_fixup2<<<512, 256, 0, stream>>>(a1, w2dq, s1, s2, cnts + 1, fl2, a2);
    k_gemm3<<<256, 256, 0, stream>>>(a2, q3, maxes + 2, s2, Out);
}

// Round 5
// 790.227 us; speedup vs baseline: 1.0808x; 1.0151x over previous
//
#include <hip/hip_runtime.h>
#include <hip/hip_fp16.h>

typedef _Float16 f16;
typedef _Float16 f16x4 __attribute__((ext_vector_type(4)));
typedef _Float16 f16x8 __attribute__((ext_vector_type(8)));
typedef float f32x4 __attribute__((ext_vector_type(4)));

#define MFMA16(a, b, c) __builtin_amdgcn_mfma_f32_16x16x32_f16((a), (b), (c), 0, 0, 0)

#define FLAG_CAP (1024 * 1024)
#define FLAG_TOL 1e-3f

// async global->LDS, 16 B per lane. LDS dest is wave-uniform base; HW writes
// base + laneid*16. Global src is per-lane (this is how we bake in the swizzle).
__device__ __forceinline__ void gld16(const f16* g, f16* l) {
    __builtin_amdgcn_global_load_lds(
        (const __attribute__((address_space(1))) unsigned int*)g,
        (__attribute__((address_space(3))) unsigned int*)l,
        16, 0, 0);
}

// ---------------- scale computation ----------------

__global__ void k_zero(float* p, int* cnt) {
    if (threadIdx.x < 3) p[threadIdx.x] = 0.f;
    if (threadIdx.x == 3) { cnt[0] = 0; cnt[1] = 0; }
}

__global__ void k_absmax(const float* __restrict__ w, int n, float* __restrict__ out) {
    float m = 0.f;
    int stride = gridDim.x * blockDim.x;
    for (int i = blockIdx.x * blockDim.x + threadIdx.x; i < n; i += stride)
        m = fmaxf(m, fabsf(w[i]));
    #pragma unroll
    for (int o = 32; o > 0; o >>= 1) m = fmaxf(m, __shfl_down(m, o));
    __shared__ float sm[4];
    int lane = threadIdx.x & 63, wv = threadIdx.x >> 6;
    if (lane == 0) sm[wv] = m;
    __syncthreads();
    if (threadIdx.x == 0) {
        float mm = fmaxf(fmaxf(sm[0], sm[1]), fmaxf(sm[2], sm[3]));
        atomicMax((unsigned int*)out, __float_as_uint(mm));  // nonneg floats only
    }
}

// W1 quant: compact q1 (fallback), fp32 dequant w1dq (fixup), duplicated+padded
// B panel q1p [512][1664] = [q|0pad | q|0pad]. fp32 ops replicate numpy.
__global__ void k_quantw1p(const float* __restrict__ w, const float* __restrict__ wmax,
                           f16* __restrict__ q1, float* __restrict__ wdq,
                           f16* __restrict__ q1p) {
    int i = blockIdx.x * blockDim.x + threadIdx.x;
    if (i >= 512 * 832) return;
    int n = i / 832, k = i - n * 832;
    float v = 0.f;
    if (k < 784) {
        float s = wmax[0] / 7.0f + 1e-8f;
        v = rintf(w[n * 784 + k] / s);
        v = fminf(fmaxf(v, -7.f), 7.f);
        q1[n * 784 + k] = (f16)v;
        wdq[n * 784 + k] = v * s;
    }
    q1p[(size_t)n * 1664 + k] = (f16)v;
    q1p[(size_t)n * 1664 + 832 + k] = (f16)v;
}

__global__ void k_quantw(const float* __restrict__ w, const float* __restrict__ wmax,
                         f16* __restrict__ q, float* __restrict__ wdq, int n) {
    float s = wmax[0] / 7.0f + 1e-8f;
    int i = blockIdx.x * blockDim.x + threadIdx.x;
    if (i < n) {
        float v = rintf(w[i] / s);
        v = fminf(fmaxf(v, -7.f), 7.f);
        q[i] = (f16)v;
        if (wdq) wdq[i] = v * s;
    }
}

__global__ void k_quantw3(const float* __restrict__ w, const float* __restrict__ wmax,
                          f16* __restrict__ q) {
    float s = wmax[0] / 7.0f + 1e-8f;
    int i = blockIdx.x * blockDim.x + threadIdx.x;
    if (i < 16 * 512) {
        float v = 0.f;
        if (i < 10 * 512) {
            v = rintf(w[i] / s);
            v = fminf(fmaxf(v, -7.f), 7.f);
        }
        q[i] = (f16)v;
    }
}

// ---------------- prep: split X fp32 -> [hi(832) | lo(832)] f16, zero-padded ----------------

__global__ void k_prep(const float* __restrict__ X, f16* __restrict__ Xs) {
    int row = blockIdx.x;
    int p = threadIdx.x;
    if (p >= 208) return;
    f16x4 h0 = (f16x4){0, 0, 0, 0}, h1 = (f16x4){0, 0, 0, 0};
    if (p < 196) {
        float4 v = *reinterpret_cast<const float4*>(X + (size_t)row * 784 + p * 4);
        float vv[4] = {v.x, v.y, v.z, v.w};
        #pragma unroll
        for (int j = 0; j < 4; ++j) {
            f16 c0 = (f16)vv[j];                 // RNE
            h0[j] = c0;
            h1[j] = (f16)(vv[j] - (float)c0);    // exact residual
        }
    }
    *reinterpret_cast<f16x4*>(Xs + (size_t)row * 1664 + p * 4) = h0;
    *reinterpret_cast<f16x4*>(Xs + (size_t)row * 1664 + 832 + p * 4) = h1;
}

// ---------------- fast GEMM1: 2-phase dbuf + swizzled LDS ----------------
// LDS layout: element (r, c) at As[r*64 + (c ^ ((r&7)<<3))]. Write-side swizzle
// is baked into the per-lane GLOBAL source column (LDS write stays linear).

__global__ __launch_bounds__(256) void k_gemm1f(
    const f16* __restrict__ A, const f16* __restrict__ B,
    const float* __restrict__ wmax, const float* __restrict__ s1p,
    f16* __restrict__ A1, int* __restrict__ flagCnt, unsigned* __restrict__ flagList)
{
    constexpr int KP = 1664;
    constexpr int NT = KP / 64;          // 26 tiles
    __shared__ __align__(16) f16 As[2][128 * 64];
    __shared__ __align__(16) f16 Bs[2][128 * 64];

    const int t = threadIdx.x;
    const int lane = t & 63, w = t >> 6;
    const int wr = w >> 1, wc = w & 1;

    // chunked XCD swizzle: the 4 N-blocks sharing an A-row-panel -> same XCD
    const int bid = blockIdx.x;
    const int lg = (bid & 7) * 256 + (bid >> 3);
    const int n0 = (lg & 3) * 128;
    const int row0 = (lg >> 2) * 128;

    f32x4 acc[4][4];
    #pragma unroll
    for (int m = 0; m < 4; ++m)
        #pragma unroll
        for (int n = 0; n < 4; ++n) acc[m][n] = (f32x4){0.f, 0.f, 0.f, 0.f};

    // staging: lane -> row lr = lane>>3 (so row&7 == lane>>3), swizzled col
    const int lr = lane >> 3;
    const int lc = (((lane & 7) ^ (lane >> 3)) * 8);
    const f16* Ab = A + (size_t)(row0 + lr) * KP + lc;
    const f16* Bb = B + (size_t)(n0 + lr) * KP + lc;

    auto STAGE = [&](int buf, int k0) {
        #pragma unroll
        for (int i = 0; i < 4; ++i) {
            int ch = w * 4 + i;                      // 16 chunks x 8 rows
            gld16(Ab + (size_t)ch * 8 * KP + k0, &As[buf][ch * 512]);
            gld16(Bb + (size_t)ch * 8 * KP + k0, &Bs[buf][ch * 512]);
        }
    };

    auto COMPUTE = [&](int buf) {
        #pragma unroll
        for (int kk = 0; kk < 2; ++kk) {
            int kb = kk * 32 + (lane >> 4) * 8;
            int ksw = kb ^ ((lane & 7) << 3);        // read-side swizzle
            f16x8 bf[4], af[4];
            #pragma unroll
            for (int n = 0; n < 4; ++n)
                bf[n] = *reinterpret_cast<const f16x8*>(&Bs[buf][(wc * 64 + n * 16 + (lane & 15)) * 64 + ksw]);
            #pragma unroll
            for (int m = 0; m < 4; ++m)
                af[m] = *reinterpret_cast<const f16x8*>(&As[buf][(wr * 64 + m * 16 + (lane & 15)) * 64 + ksw]);
            #pragma unroll
            for (int m = 0; m < 4; ++m)
                #pragma unroll
                for (int n = 0; n < 4; ++n)
                    acc[m][n] = MFMA16(af[m], bf[n], acc[m][n]);
        }
    };

    STAGE(0, 0);
    __syncthreads();                                 // tile 0 resident
    for (int tt = 0; tt < NT; tt += 2) {
        if (tt + 1 < NT) STAGE(1, (tt + 1) * 64);    // issue next while computing
        COMPUTE(0);
        __syncthreads();                             // drain: tile tt+1 resident
        if (tt + 2 < NT) STAGE(0, (tt + 2) * 64);
        COMPUTE(1);
        __syncthreads();
    }

    float sw = wmax[0] / 7.0f + 1e-8f;
    float s1v = s1p[0];
    #pragma unroll
    for (int m = 0; m < 4; ++m)
        #pragma unroll
        for (int n = 0; n < 4; ++n)
            #pragma unroll
            for (int j = 0; j < 4; ++j) {
                int row = row0 + wr * 64 + m * 16 + (lane >> 4) * 4 + j;
                int col = n0 + wc * 64 + n * 16 + (lane & 15);
                float h = sw * acc[m][n][j];
                float r = fmaxf(h, 0.f) / s1v;
                float qv = fminf(rintf(r), 15.f);
                A1[(size_t)row * 512 + col] = (f16)qv;
                float fr = r - floorf(r);
                if (fabsf(fr - 0.5f) < FLAG_TOL) {
                    int p = atomicAdd(flagCnt, 1);
                    if (p < FLAG_CAP) flagList[p] = (unsigned)(row * 512 + col);
                }
            }
}

// ---------------- fallback GEMM1 (round-3, in-kernel split) ----------------

__global__ __launch_bounds__(256) void k_gemm1s(
    const float* __restrict__ X, const f16* __restrict__ Q1,
    const float* __restrict__ wmax, const float* __restrict__ s1p,
    f16* __restrict__ A1, int* __restrict__ flagCnt, unsigned* __restrict__ flagList)
{
    __shared__ __align__(16) f16 As0[128][72];
    __shared__ __align__(16) f16 As1[128][72];
    __shared__ __align__(16) f16 Bs[128][72];

    const int t = threadIdx.x;
    const int row0 = blockIdx.y * 128;
    const int n0 = blockIdx.x * 128;
    const int lane = t & 63, wv = t >> 6;
    const int wr = wv >> 1, wc = wv & 1;

    f32x4 acc[4][4];
    #pragma unroll
    for (int m = 0; m < 4; ++m)
        #pragma unroll
        for (int n = 0; n < 4; ++n) acc[m][n] = (f32x4){0.f, 0.f, 0.f, 0.f};

    for (int k0 = 0; k0 < 784; k0 += 64) {
        #pragma unroll
        for (int i = 0; i < 8; ++i) {
            int f = t + 256 * i;
            int r = f >> 4, c = f & 15;
            int gk = k0 + c * 4;
            float4 v = make_float4(0.f, 0.f, 0.f, 0.f);
            if (gk < 784)
                v = *reinterpret_cast<const float4*>(X + (size_t)(row0 + r) * 784 + gk);
            float vv[4] = {v.x, v.y, v.z, v.w};
            f16x4 h0, h1;
            #pragma unroll
            for (int j = 0; j < 4; ++j) {
                f16 c0 = (f16)vv[j];
                h0[j] = c0;
                h1[j] = (f16)(vv[j] - (float)c0);
            }
            *reinterpret_cast<f16x4*>(&As0[r][c * 4]) = h0;
            *reinterpret_cast<f16x4*>(&As1[r][c * 4]) = h1;
        }
        #pragma unroll
        for (int i = 0; i < 4; ++i) {
            int f = t + 256 * i;
            int r = f >> 3, c = f & 7;
            int gk = k0 + c * 8;
            uint4 u = make_uint4(0u, 0u, 0u, 0u);
            if (gk < 784)
                u = *reinterpret_cast<const uint4*>(Q1 + (size_t)(n0 + r) * 784 + gk);
            *reinterpret_cast<uint4*>(&Bs[r][c * 8]) = u;
        }
        __syncthreads();

        #pragma unroll
        for (int kk = 0; kk < 2; ++kk) {
            int kb = kk * 32 + (lane >> 4) * 8;
            f16x8 bf[4], a0[4], a1f[4];
            #pragma unroll
            for (int n = 0; n < 4; ++n)
                bf[n] = *reinterpret_cast<const f16x8*>(&Bs[wc * 64 + n * 16 + (lane & 15)][kb]);
            #pragma unroll
            for (int m = 0; m < 4; ++m) {
                a0[m]  = *reinterpret_cast<const f16x8*>(&As0[wr * 64 + m * 16 + (lane & 15)][kb]);
                a1f[m] = *reinterpret_cast<const f16x8*>(&As1[wr * 64 + m * 16 + (lane & 15)][kb]);
            }
            #pragma unroll
            for (int m = 0; m < 4; ++m)
                #pragma unroll
                for (int n = 0; n < 4; ++n) {
                    acc[m][n] = MFMA16(a0[m],  bf[n], acc[m][n]);
                    acc[m][n] = MFMA16(a1f[m], bf[n], acc[m][n]);
                }
        }
        __syncthreads();
    }

    float sw = wmax[0] / 7.0f + 1e-8f;
    float s1v = s1p[0];
    #pragma unroll
    for (int m = 0; m < 4; ++m)
        #pragma unroll
        for (int n = 0; n < 4; ++n)
            #pragma unroll
            for (int j = 0; j < 4; ++j) {
                int row = row0 + wr * 64 + m * 16 + (lane >> 4) * 4 + j;
                int col = n0 + wc * 64 + n * 16 + (lane & 15);
                float h = sw * acc[m][n][j];
                float r = fmaxf(h, 0.f) / s1v;
                float qv = fminf(rintf(r), 15.f);
                A1[(size_t)row * 512 + col] = (f16)qv;
                float fr = r - floorf(r);
                if (fabsf(fr - 0.5f) < FLAG_TOL) {
                    int p = atomicAdd(flagCnt, 1);
                    if (p < FLAG_CAP) flagList[p] = (unsigned)(row * 512 + col);
                }
            }
}

// ---------------- fixup1: BLAS-replicating sequential fp32 FMA ----------------

__global__ void k_fixup1(const float* __restrict__ X, const float* __restrict__ W1dq,
                         const float* __restrict__ s1p,
                         const int* __restrict__ flagCnt, const unsigned* __restrict__ flagList,
                         f16* __restrict__ A1)
{
    int tid = blockIdx.x * blockDim.x + threadIdx.x;
    int nthr = gridDim.x * blockDim.x;
    int n = flagCnt[0];
    if (n > FLAG_CAP) n = FLAG_CAP;
    float s1 = s1p[0];
    for (int i = tid; i < n; i += nthr) {
        unsigned idx = flagList[i];
        int row = (int)(idx >> 9), col = (int)(idx & 511);
        const float* xr = X + (size_t)row * 784;
        const float* wr = W1dq + (size_t)col * 784;
        float acc = 0.f;
        for (int k = 0; k < 784; ++k)
            acc = fmaf(xr[k], wr[k], acc);
        float tq = fmaxf(acc, 0.f) / s1;
        float code = fminf(rintf(tq), 15.f);
        A1[(size_t)row * 512 + col] = (f16)code;
    }
}

// ---------------- fast GEMM2: 2-phase dbuf + swizzled LDS, fp64 epilogue ----------------

__global__ __launch_bounds__(256) void k_gemm2f(
    const f16* __restrict__ A, const f16* __restrict__ B,
    const float* __restrict__ wmax, const float* __restrict__ s1p, const float* __restrict__ s2p,
    f16* __restrict__ A2, int* __restrict__ flagCnt, unsigned* __restrict__ flagList)
{
    constexpr int KP = 512;
    constexpr int NT = KP / 64;          // 8 tiles
    __shared__ __align__(16) f16 As[2][128 * 64];
    __shared__ __align__(16) f16 Bs[2][128 * 64];

    const int t = threadIdx.x;
    const int lane = t & 63, w = t >> 6;
    const int wr = w >> 1, wc = w & 1;

    const int bid = blockIdx.x;
    const int lg = (bid & 7) * 256 + (bid >> 3);
    const int n0 = (lg & 3) * 128;
    const int row0 = (lg >> 2) * 128;

    f32x4 acc[4][4];
    #pragma unroll
    for (int m = 0; m < 4; ++m)
        #pragma unroll
        for (int n = 0; n < 4; ++n) acc[m][n] = (f32x4){0.f, 0.f, 0.f, 0.f};

    const int lr = lane >> 3;
    const int lc = (((lane & 7) ^ (lane >> 3)) * 8);
    const f16* Ab = A + (size_t)(row0 + lr) * KP + lc;
    const f16* Bb = B + (size_t)(n0 + lr) * KP + lc;

    auto STAGE = [&](int buf, int k0) {
        #pragma unroll
        for (int i = 0; i < 4; ++i) {
            int ch = w * 4 + i;
            gld16(Ab + (size_t)ch * 8 * KP + k0, &As[buf][ch * 512]);
            gld16(Bb + (size_t)ch * 8 * KP + k0, &Bs[buf][ch * 512]);
        }
    };

    auto COMPUTE = [&](int buf) {
        #pragma unroll
        for (int kk = 0; kk < 2; ++kk) {
            int kb = kk * 32 + (lane >> 4) * 8;
            int ksw = kb ^ ((lane & 7) << 3);
            f16x8 bf[4], af[4];
            #pragma unroll
            for (int n = 0; n < 4; ++n)
                bf[n] = *reinterpret_cast<const f16x8*>(&Bs[buf][(wc * 64 + n * 16 + (lane & 15)) * 64 + ksw]);
            #pragma unroll
            for (int m = 0; m < 4; ++m)
                af[m] = *reinterpret_cast<const f16x8*>(&As[buf][(wr * 64 + m * 16 + (lane & 15)) * 64 + ksw]);
            #pragma unroll
            for (int m = 0; m < 4; ++m)
                #pragma unroll
                for (int n = 0; n < 4; ++n)
                    acc[m][n] = MFMA16(af[m], bf[n], acc[m][n]);
        }
    };

    STAGE(0, 0);
    __syncthreads();
    for (int tt = 0; tt < NT; tt += 2) {
        if (tt + 1 < NT) STAGE(1, (tt + 1) * 64);
        COMPUTE(0);
        __syncthreads();
        if (tt + 2 < NT) STAGE(0, (tt + 2) * 64);
        COMPUTE(1);
        __syncthreads();
    }

    double cs = (double)s1p[0] * (double)(wmax[0] / 7.0f + 1e-8f);
    double s2v = (double)s2p[0];
    #pragma unroll
    for (int m = 0; m < 4; ++m)
        #pragma unroll
        for (int n = 0; n < 4; ++n)
            #pragma unroll
            for (int j = 0; j < 4; ++j) {
                int row = row0 + wr * 64 + m * 16 + (lane >> 4) * 4 + j;
                int col = n0 + wc * 64 + n * 16 + (lane & 15);
                double r = fmax((double)acc[m][n][j] * cs, 0.0) / s2v;
                double qv = fmin(rint(r), 15.0);
                A2[(size_t)row * 512 + col] = (f16)qv;
                double fr = r - floor(r);
                if (fabs(fr - 0.5) < (double)FLAG_TOL && r < 16.0) {
                    int p = atomicAdd(flagCnt, 1);
                    if (p < FLAG_CAP) flagList[p] = (unsigned)(row * 512 + col);
                }
            }
}

// ---------------- fixup2 ----------------

__global__ void k_fixup2(const f16* __restrict__ A1, const float* __restrict__ W2dq,
                         const float* __restrict__ s1p, const float* __restrict__ s2p,
                         const int* __restrict__ flagCnt, const unsigned* __restrict__ flagList,
                         f16* __restrict__ A2)
{
    int tid = blockIdx.x * blockDim.x + threadIdx.x;
    int nthr = gridDim.x * blockDim.x;
    int n = flagCnt[0];
    if (n > FLAG_CAP) n = FLAG_CAP;
    float s1 = s1p[0], s2 = s2p[0];
    for (int i = tid; i < n; i += nthr) {
        unsigned idx = flagList[i];
        int row = (int)(idx >> 9), col = (int)(idx & 511);
        const f16* ar = A1 + (size_t)row * 512;
        const float* wr = W2dq + (size_t)col * 512;
        float acc = 0.f;
        for (int k = 0; k < 512; ++k) {
            float adq = (float)ar[k] * s1;
            acc = fmaf(adq, wr[k], acc);
        }
        float tq = fmaxf(acc, 0.f) / s2;
        float code = fminf(rintf(tq), 15.f);
        A2[(size_t)row * 512 + col] = (f16)code;
    }
}

// ---------------- GEMM3: [65536,512] @ [16,512]^T -> fp32 logits ----------------

__global__ __launch_bounds__(256) void k_gemm3(
    const f16* __restrict__ A2, const f16* __restrict__ Q3,
    const float* __restrict__ wmax, const float* __restrict__ s2p,
    float* __restrict__ Out)
{
    __shared__ __align__(16) f16 As[256][72];
    __shared__ __align__(16) f16 Bs[16][72];

    const int t = threadIdx.x;
    const int row0 = blockIdx.x * 256;
    const int lane = t & 63, wv = t >> 6;

    f32x4 acc[4];
    #pragma unroll
    for (int m = 0; m < 4; ++m) acc[m] = (f32x4){0.f, 0.f, 0.f, 0.f};

    for (int k0 = 0; k0 < 512; k0 += 64) {
        #pragma unroll
        for (int i = 0; i < 8; ++i) {
            int f = t + 256 * i;
            int r = f >> 3, c = f & 7;
            *reinterpret_cast<uint4*>(&As[r][c * 8]) =
                *reinterpret_cast<const uint4*>(A2 + (size_t)(row0 + r) * 512 + k0 + c * 8);
        }
        if (t < 128) {
            int r = t >> 3, c = t & 7;
            *reinterpret_cast<uint4*>(&Bs[r][c * 8]) =
                *reinterpret_cast<const uint4*>(Q3 + (size_t)r * 512 + k0 + c * 8);
        }
        __syncthreads();

        #pragma unroll
        for (int kk = 0; kk < 2; ++kk) {
            int kb = kk * 32 + (lane >> 4) * 8;
            f16x8 bf = *reinterpret_cast<const f16x8*>(&Bs[lane & 15][kb]);
            #pragma unroll
            for (int m = 0; m < 4; ++m) {
                f16x8 af = *reinterpret_cast<const f16x8*>(&As[wv * 64 + m * 16 + (lane & 15)][kb]);
                acc[m] = MFMA16(af, bf, acc[m]);
            }
        }
        __syncthreads();
    }

    double cs = (double)s2p[0] * (double)(wmax[0] / 7.0f + 1e-8f);
    #pragma unroll
    for (int m = 0; m < 4; ++m)
        #pragma unroll
        for (int j = 0; j < 4; ++j) {
            int row = row0 + wv * 64 + m * 16 + (lane >> 4) * 4 + j;
            int col = lane & 15;
            if (col < 10)
                Out[(size_t)row * 10 + col] = (float)((double)acc[m][j] * cs);
        }
}

// ---------------- launch ----------------

extern "C" void kernel_launch(void* const* d_in, const int* in_sizes, int n_in,
                              void* d_out, int out_size, void* d_ws, size_t ws_size,
                              hipStream_t stream)
{
    (void)in_sizes; (void)n_in; (void)out_size;

    const float* X  = (const float*)d_in[0];
    const float* W1 = (const float*)d_in[1];
    const float* W2 = (const float*)d_in[2];
    const float* W3 = (const float*)d_in[3];
    const float* s1 = (const float*)d_in[4];
    const float* s2 = (const float*)d_in[5];
    float* Out = (float*)d_out;

    char* ws = (char*)d_ws;
    float* maxes   = (float*)ws;
    int*   cnts    = (int*)(ws + 16);
    f16*   q1      = (f16*)(ws + 4096);                           // 802816 B
    f16*   q2      = (f16*)(ws + (size_t)(1u << 20));             // 524288 B
    f16*   q3      = (f16*)(ws + (size_t)(1u << 20) + 600000);    // 16384 B
    f16*   q1p     = (f16*)(ws + (size_t)(2u << 20));             // 1703936 B
    float* w1dq    = (float*)(ws + (size_t)(4u << 20));           // 1605632 B
    float* w2dq    = (float*)(ws + (size_t)(6u << 20));           // 1048576 B
    f16*   a1      = (f16*)(ws + (size_t)(8u << 20));             // 64 MB
    f16*   a2      = (f16*)(ws + (size_t)(72u << 20));            // 64 MB
    unsigned* fl1  = (unsigned*)(ws + (size_t)(136u << 20));      // 4 MB
    unsigned* fl2  = (unsigned*)(ws + (size_t)(140u << 20));      // 4 MB
    f16*   Xs      = (f16*)(ws + (size_t)(144u << 20));           // 218 MB (fast path)

    const bool big = ws_size >= ((size_t)356 << 20);

    k_zero<<<1, 64, 0, stream>>>(maxes, cnts);
    k_absmax<<<256, 256, 0, stream>>>(W1, 512 * 784, maxes + 0);
    k_absmax<<<256, 256, 0, stream>>>(W2, 512 * 512, maxes + 1);
    k_absmax<<<8, 256, 0, stream>>>(W3, 10 * 512, maxes + 2);
    k_quantw1p<<<(512 * 832 + 255) / 256, 256, 0, stream>>>(W1, maxes + 0, q1, w1dq, q1p);
    k_quantw<<<(512 * 512 + 255) / 256, 256, 0, stream>>>(W2, maxes + 1, q2, w2dq, 512 * 512);
    k_quantw3<<<(16 * 512 + 255) / 256, 256, 0, stream>>>(W3, maxes + 2, q3);

    if (big) {
        k_prep<<<65536, 256, 0, stream>>>(X, Xs);
        k_gemm1f<<<2048, 256, 0, stream>>>(Xs, q1p, maxes + 0, s1, a1, cnts + 0, fl1);
    } else {
        k_gemm1s<<<dim3(4, 512), 256, 0, stream>>>(X, q1, maxes + 0, s1, a1, cnts + 0, fl1);
    }
    k_fixup1<<<512, 256, 0, stream>>>(X, w1dq, s1, cnts + 0, fl1, a1);
    k_gemm2f<<<2048, 256, 0, stream>>>(a1, q2, maxes + 1, s1, s2, a2, cnts + 1, fl2);
    k_fixup2<<<512, 256, 0, stream>>>(a1, w2dq, s1, s2, cnts + 1, fl2, a2);
    k_gemm3<<<256, 256, 0, stream>>>(a2, q3, maxes + 2, s2, Out);
}

// Round 6
// 725.055 us; speedup vs baseline: 1.1780x; 1.0899x over previous
//
#include <hip/hip_runtime.h>
#include <hip/hip_fp16.h>

typedef _Float16 f16;
typedef _Float16 f16x4 __attribute__((ext_vector_type(4)));
typedef _Float16 f16x8 __attribute__((ext_vector_type(8)));
typedef float f32x4 __attribute__((ext_vector_type(4)));

#define MFMA16(a, b, c) __builtin_amdgcn_mfma_f32_16x16x32_f16((a), (b), (c), 0, 0, 0)

#define FLAG_CAP (1024 * 1024)
#define FLAG_TOL 1e-3f

// async global->LDS, 16 B per lane. LDS dest is wave-uniform base; HW writes
// base + laneid*16. Global src is per-lane (this is how we bake in the swizzle).
__device__ __forceinline__ void gld16(const f16* g, f16* l) {
    __builtin_amdgcn_global_load_lds(
        (const __attribute__((address_space(1))) unsigned int*)g,
        (__attribute__((address_space(3))) unsigned int*)l,
        16, 0, 0);
}

// ---------------- scale computation ----------------

__global__ void k_zero(float* p, int* cnt) {
    if (threadIdx.x < 3) p[threadIdx.x] = 0.f;
    if (threadIdx.x == 3) { cnt[0] = 0; cnt[1] = 0; }
}

__global__ void k_absmax(const float* __restrict__ w, int n, float* __restrict__ out) {
    float m = 0.f;
    int stride = gridDim.x * blockDim.x;
    for (int i = blockIdx.x * blockDim.x + threadIdx.x; i < n; i += stride)
        m = fmaxf(m, fabsf(w[i]));
    #pragma unroll
    for (int o = 32; o > 0; o >>= 1) m = fmaxf(m, __shfl_down(m, o));
    __shared__ float sm[4];
    int lane = threadIdx.x & 63, wv = threadIdx.x >> 6;
    if (lane == 0) sm[wv] = m;
    __syncthreads();
    if (threadIdx.x == 0) {
        float mm = fmaxf(fmaxf(sm[0], sm[1]), fmaxf(sm[2], sm[3]));
        atomicMax((unsigned int*)out, __float_as_uint(mm));  // nonneg floats only
    }
}

// W1 quant: compact q1 (fallback), fp32 dequant w1dq (fixup), duplicated+padded
// B panel q1p [512][1664] = [q|0pad | q|0pad]. fp32 ops replicate numpy.
__global__ void k_quantw1p(const float* __restrict__ w, const float* __restrict__ wmax,
                           f16* __restrict__ q1, float* __restrict__ wdq,
                           f16* __restrict__ q1p) {
    int i = blockIdx.x * blockDim.x + threadIdx.x;
    if (i >= 512 * 832) return;
    int n = i / 832, k = i - n * 832;
    float v = 0.f;
    if (k < 784) {
        float s = wmax[0] / 7.0f + 1e-8f;
        v = rintf(w[n * 784 + k] / s);
        v = fminf(fmaxf(v, -7.f), 7.f);
        q1[n * 784 + k] = (f16)v;
        wdq[n * 784 + k] = v * s;
    }
    q1p[(size_t)n * 1664 + k] = (f16)v;
    q1p[(size_t)n * 1664 + 832 + k] = (f16)v;
}

__global__ void k_quantw(const float* __restrict__ w, const float* __restrict__ wmax,
                         f16* __restrict__ q, float* __restrict__ wdq, int n) {
    float s = wmax[0] / 7.0f + 1e-8f;
    int i = blockIdx.x * blockDim.x + threadIdx.x;
    if (i < n) {
        float v = rintf(w[i] / s);
        v = fminf(fmaxf(v, -7.f), 7.f);
        q[i] = (f16)v;
        if (wdq) wdq[i] = v * s;
    }
}

__global__ void k_quantw3(const float* __restrict__ w, const float* __restrict__ wmax,
                          f16* __restrict__ q) {
    float s = wmax[0] / 7.0f + 1e-8f;
    int i = blockIdx.x * blockDim.x + threadIdx.x;
    if (i < 16 * 512) {
        float v = 0.f;
        if (i < 10 * 512) {
            v = rintf(w[i] / s);
            v = fminf(fmaxf(v, -7.f), 7.f);
        }
        q[i] = (f16)v;
    }
}

// ---------------- prep: split X fp32 -> [hi(832) | lo(832)] f16, zero-padded ----------------

__global__ void k_prep(const float* __restrict__ X, f16* __restrict__ Xs) {
    int row = blockIdx.x;
    int p = threadIdx.x;
    if (p >= 208) return;
    f16x4 h0 = (f16x4){0, 0, 0, 0}, h1 = (f16x4){0, 0, 0, 0};
    if (p < 196) {
        float4 v = *reinterpret_cast<const float4*>(X + (size_t)row * 784 + p * 4);
        float vv[4] = {v.x, v.y, v.z, v.w};
        #pragma unroll
        for (int j = 0; j < 4; ++j) {
            f16 c0 = (f16)vv[j];                 // RNE
            h0[j] = c0;
            h1[j] = (f16)(vv[j] - (float)c0);    // exact residual
        }
    }
    *reinterpret_cast<f16x4*>(Xs + (size_t)row * 1664 + p * 4) = h0;
    *reinterpret_cast<f16x4*>(Xs + (size_t)row * 1664 + 832 + p * 4) = h1;
}

// ---------------- fast GEMM1: m97 single-buffer + swizzled LDS + XCD swizzle ----------------
// LDS layout: element (r, c) at As[r*64 + (c ^ ((r&7)<<3))]. Write-side swizzle
// baked into per-lane GLOBAL source col (LDS write linear). 32KB LDS -> 4 blk/CU;
// implicit wave-level overlap (m114) does the pipelining.

__global__ __launch_bounds__(256, 4) void k_gemm1f(
    const f16* __restrict__ A, const f16* __restrict__ B,
    const float* __restrict__ wmax, const float* __restrict__ s1p,
    f16* __restrict__ A1, int* __restrict__ flagCnt, unsigned* __restrict__ flagList)
{
    constexpr int KP = 1664;
    constexpr int NT = KP / 64;          // 26 tiles
    __shared__ __align__(16) f16 As[128 * 64];
    __shared__ __align__(16) f16 Bs[128 * 64];

    const int t = threadIdx.x;
    const int lane = t & 63, w = t >> 6;
    const int wr = w >> 1, wc = w & 1;

    // chunked XCD swizzle: the 4 N-blocks sharing an A-row-panel -> same XCD
    const int bid = blockIdx.x;
    const int lg = (bid & 7) * 256 + (bid >> 3);
    const int n0 = (lg & 3) * 128;
    const int row0 = (lg >> 2) * 128;

    f32x4 acc[4][4];
    #pragma unroll
    for (int m = 0; m < 4; ++m)
        #pragma unroll
        for (int n = 0; n < 4; ++n) acc[m][n] = (f32x4){0.f, 0.f, 0.f, 0.f};

    // staging: lane -> row lr = lane>>3 (so row&7 == lane>>3), swizzled col
    const int lr = lane >> 3;
    const int lc = (((lane & 7) ^ (lane >> 3)) * 8);
    const f16* Ab = A + (size_t)(row0 + lr) * KP + lc;
    const f16* Bb = B + (size_t)(n0 + lr) * KP + lc;

    for (int tt = 0; tt < NT; ++tt) {
        const int k0 = tt * 64;
        #pragma unroll
        for (int i = 0; i < 4; ++i) {
            int ch = w * 4 + i;                      // 16 chunks x 8 rows
            gld16(Ab + (size_t)ch * 8 * KP + k0, &As[ch * 512]);
            gld16(Bb + (size_t)ch * 8 * KP + k0, &Bs[ch * 512]);
        }
        __syncthreads();                             // drains vmcnt: tile resident

        #pragma unroll
        for (int kk = 0; kk < 2; ++kk) {
            int kb = kk * 32 + (lane >> 4) * 8;
            int ksw = kb ^ ((lane & 7) << 3);        // read-side swizzle
            f16x8 bf[4], af[4];
            #pragma unroll
            for (int n = 0; n < 4; ++n)
                bf[n] = *reinterpret_cast<const f16x8*>(&Bs[(wc * 64 + n * 16 + (lane & 15)) * 64 + ksw]);
            #pragma unroll
            for (int m = 0; m < 4; ++m)
                af[m] = *reinterpret_cast<const f16x8*>(&As[(wr * 64 + m * 16 + (lane & 15)) * 64 + ksw]);
            #pragma unroll
            for (int m = 0; m < 4; ++m)
                #pragma unroll
                for (int n = 0; n < 4; ++n)
                    acc[m][n] = MFMA16(af[m], bf[n], acc[m][n]);
        }
        __syncthreads();                             // safe to overwrite next iter
    }

    float sw = wmax[0] / 7.0f + 1e-8f;
    float s1v = s1p[0];
    #pragma unroll
    for (int m = 0; m < 4; ++m)
        #pragma unroll
        for (int n = 0; n < 4; ++n)
            #pragma unroll
            for (int j = 0; j < 4; ++j) {
                int row = row0 + wr * 64 + m * 16 + (lane >> 4) * 4 + j;
                int col = n0 + wc * 64 + n * 16 + (lane & 15);
                float h = sw * acc[m][n][j];
                float r = fmaxf(h, 0.f) / s1v;
                float qv = fminf(rintf(r), 15.f);
                A1[(size_t)row * 512 + col] = (f16)qv;
                float fr = r - floorf(r);
                if (fabsf(fr - 0.5f) < FLAG_TOL) {
                    int p = atomicAdd(flagCnt, 1);
                    if (p < FLAG_CAP) flagList[p] = (unsigned)(row * 512 + col);
                }
            }
}

// ---------------- fallback GEMM1 (round-3, in-kernel split) ----------------

__global__ __launch_bounds__(256) void k_gemm1s(
    const float* __restrict__ X, const f16* __restrict__ Q1,
    const float* __restrict__ wmax, const float* __restrict__ s1p,
    f16* __restrict__ A1, int* __restrict__ flagCnt, unsigned* __restrict__ flagList)
{
    __shared__ __align__(16) f16 As0[128][72];
    __shared__ __align__(16) f16 As1[128][72];
    __shared__ __align__(16) f16 Bs[128][72];

    const int t = threadIdx.x;
    const int row0 = blockIdx.y * 128;
    const int n0 = blockIdx.x * 128;
    const int lane = t & 63, wv = t >> 6;
    const int wr = wv >> 1, wc = wv & 1;

    f32x4 acc[4][4];
    #pragma unroll
    for (int m = 0; m < 4; ++m)
        #pragma unroll
        for (int n = 0; n < 4; ++n) acc[m][n] = (f32x4){0.f, 0.f, 0.f, 0.f};

    for (int k0 = 0; k0 < 784; k0 += 64) {
        #pragma unroll
        for (int i = 0; i < 8; ++i) {
            int f = t + 256 * i;
            int r = f >> 4, c = f & 15;
            int gk = k0 + c * 4;
            float4 v = make_float4(0.f, 0.f, 0.f, 0.f);
            if (gk < 784)
                v = *reinterpret_cast<const float4*>(X + (size_t)(row0 + r) * 784 + gk);
            float vv[4] = {v.x, v.y, v.z, v.w};
            f16x4 h0, h1;
            #pragma unroll
            for (int j = 0; j < 4; ++j) {
                f16 c0 = (f16)vv[j];
                h0[j] = c0;
                h1[j] = (f16)(vv[j] - (float)c0);
            }
            *reinterpret_cast<f16x4*>(&As0[r][c * 4]) = h0;
            *reinterpret_cast<f16x4*>(&As1[r][c * 4]) = h1;
        }
        #pragma unroll
        for (int i = 0; i < 4; ++i) {
            int f = t + 256 * i;
            int r = f >> 3, c = f & 7;
            int gk = k0 + c * 8;
            uint4 u = make_uint4(0u, 0u, 0u, 0u);
            if (gk < 784)
                u = *reinterpret_cast<const uint4*>(Q1 + (size_t)(n0 + r) * 784 + gk);
            *reinterpret_cast<uint4*>(&Bs[r][c * 8]) = u;
        }
        __syncthreads();

        #pragma unroll
        for (int kk = 0; kk < 2; ++kk) {
            int kb = kk * 32 + (lane >> 4) * 8;
            f16x8 bf[4], a0[4], a1f[4];
            #pragma unroll
            for (int n = 0; n < 4; ++n)
                bf[n] = *reinterpret_cast<const f16x8*>(&Bs[wc * 64 + n * 16 + (lane & 15)][kb]);
            #pragma unroll
            for (int m = 0; m < 4; ++m) {
                a0[m]  = *reinterpret_cast<const f16x8*>(&As0[wr * 64 + m * 16 + (lane & 15)][kb]);
                a1f[m] = *reinterpret_cast<const f16x8*>(&As1[wr * 64 + m * 16 + (lane & 15)][kb]);
            }
            #pragma unroll
            for (int m = 0; m < 4; ++m)
                #pragma unroll
                for (int n = 0; n < 4; ++n) {
                    acc[m][n] = MFMA16(a0[m],  bf[n], acc[m][n]);
                    acc[m][n] = MFMA16(a1f[m], bf[n], acc[m][n]);
                }
        }
        __syncthreads();
    }

    float sw = wmax[0] / 7.0f + 1e-8f;
    float s1v = s1p[0];
    #pragma unroll
    for (int m = 0; m < 4; ++m)
        #pragma unroll
        for (int n = 0; n < 4; ++n)
            #pragma unroll
            for (int j = 0; j < 4; ++j) {
                int row = row0 + wr * 64 + m * 16 + (lane >> 4) * 4 + j;
                int col = n0 + wc * 64 + n * 16 + (lane & 15);
                float h = sw * acc[m][n][j];
                float r = fmaxf(h, 0.f) / s1v;
                float qv = fminf(rintf(r), 15.f);
                A1[(size_t)row * 512 + col] = (f16)qv;
                float fr = r - floorf(r);
                if (fabsf(fr - 0.5f) < FLAG_TOL) {
                    int p = atomicAdd(flagCnt, 1);
                    if (p < FLAG_CAP) flagList[p] = (unsigned)(row * 512 + col);
                }
            }
}

// ---------------- fixup1: BLAS-replicating sequential fp32 FMA ----------------

__global__ void k_fixup1(const float* __restrict__ X, const float* __restrict__ W1dq,
                         const float* __restrict__ s1p,
                         const int* __restrict__ flagCnt, const unsigned* __restrict__ flagList,
                         f16* __restrict__ A1)
{
    int tid = blockIdx.x * blockDim.x + threadIdx.x;
    int nthr = gridDim.x * blockDim.x;
    int n = flagCnt[0];
    if (n > FLAG_CAP) n = FLAG_CAP;
    float s1 = s1p[0];
    for (int i = tid; i < n; i += nthr) {
        unsigned idx = flagList[i];
        int row = (int)(idx >> 9), col = (int)(idx & 511);
        const float* xr = X + (size_t)row * 784;
        const float* wr = W1dq + (size_t)col * 784;
        float acc = 0.f;
        for (int k = 0; k < 784; ++k)
            acc = fmaf(xr[k], wr[k], acc);
        float tq = fmaxf(acc, 0.f) / s1;
        float code = fminf(rintf(tq), 15.f);
        A1[(size_t)row * 512 + col] = (f16)code;
    }
}

// ---------------- fast GEMM2: m97 single-buffer + swizzle, fp64 epilogue ----------------

__global__ __launch_bounds__(256, 4) void k_gemm2f(
    const f16* __restrict__ A, const f16* __restrict__ B,
    const float* __restrict__ wmax, const float* __restrict__ s1p, const float* __restrict__ s2p,
    f16* __restrict__ A2, int* __restrict__ flagCnt, unsigned* __restrict__ flagList)
{
    constexpr int KP = 512;
    constexpr int NT = KP / 64;          // 8 tiles
    __shared__ __align__(16) f16 As[128 * 64];
    __shared__ __align__(16) f16 Bs[128 * 64];

    const int t = threadIdx.x;
    const int lane = t & 63, w = t >> 6;
    const int wr = w >> 1, wc = w & 1;

    const int bid = blockIdx.x;
    const int lg = (bid & 7) * 256 + (bid >> 3);
    const int n0 = (lg & 3) * 128;
    const int row0 = (lg >> 2) * 128;

    f32x4 acc[4][4];
    #pragma unroll
    for (int m = 0; m < 4; ++m)
        #pragma unroll
        for (int n = 0; n < 4; ++n) acc[m][n] = (f32x4){0.f, 0.f, 0.f, 0.f};

    const int lr = lane >> 3;
    const int lc = (((lane & 7) ^ (lane >> 3)) * 8);
    const f16* Ab = A + (size_t)(row0 + lr) * KP + lc;
    const f16* Bb = B + (size_t)(n0 + lr) * KP + lc;

    for (int tt = 0; tt < NT; ++tt) {
        const int k0 = tt * 64;
        #pragma unroll
        for (int i = 0; i < 4; ++i) {
            int ch = w * 4 + i;
            gld16(Ab + (size_t)ch * 8 * KP + k0, &As[ch * 512]);
            gld16(Bb + (size_t)ch * 8 * KP + k0, &Bs[ch * 512]);
        }
        __syncthreads();

        #pragma unroll
        for (int kk = 0; kk < 2; ++kk) {
            int kb = kk * 32 + (lane >> 4) * 8;
            int ksw = kb ^ ((lane & 7) << 3);
            f16x8 bf[4], af[4];
            #pragma unroll
            for (int n = 0; n < 4; ++n)
                bf[n] = *reinterpret_cast<const f16x8*>(&Bs[(wc * 64 + n * 16 + (lane & 15)) * 64 + ksw]);
            #pragma unroll
            for (int m = 0; m < 4; ++m)
                af[m] = *reinterpret_cast<const f16x8*>(&As[(wr * 64 + m * 16 + (lane & 15)) * 64 + ksw]);
            #pragma unroll
            for (int m = 0; m < 4; ++m)
                #pragma unroll
                for (int n = 0; n < 4; ++n)
                    acc[m][n] = MFMA16(af[m], bf[n], acc[m][n]);
        }
        __syncthreads();
    }

    double cs = (double)s1p[0] * (double)(wmax[0] / 7.0f + 1e-8f);
    double s2v = (double)s2p[0];
    #pragma unroll
    for (int m = 0; m < 4; ++m)
        #pragma unroll
        for (int n = 0; n < 4; ++n)
            #pragma unroll
            for (int j = 0; j < 4; ++j) {
                int row = row0 + wr * 64 + m * 16 + (lane >> 4) * 4 + j;
                int col = n0 + wc * 64 + n * 16 + (lane & 15);
                double r = fmax((double)acc[m][n][j] * cs, 0.0) / s2v;
                double qv = fmin(rint(r), 15.0);
                A2[(size_t)row * 512 + col] = (f16)qv;
                double fr = r - floor(r);
                if (fabs(fr - 0.5) < (double)FLAG_TOL && r < 16.0) {
                    int p = atomicAdd(flagCnt, 1);
                    if (p < FLAG_CAP) flagList[p] = (unsigned)(row * 512 + col);
                }
            }
}

// ---------------- fixup2 ----------------

__global__ void k_fixup2(const f16* __restrict__ A1, const float* __restrict__ W2dq,
                         const float* __restrict__ s1p, const float* __restrict__ s2p,
                         const int* __restrict__ flagCnt, const unsigned* __restrict__ flagList,
                         f16* __restrict__ A2)
{
    int tid = blockIdx.x * blockDim.x + threadIdx.x;
    int nthr = gridDim.x * blockDim.x;
    int n = flagCnt[0];
    if (n > FLAG_CAP) n = FLAG_CAP;
    float s1 = s1p[0], s2 = s2p[0];
    for (int i = tid; i < n; i += nthr) {
        unsigned idx = flagList[i];
        int row = (int)(idx >> 9), col = (int)(idx & 511);
        const f16* ar = A1 + (size_t)row * 512;
        const float* wr = W2dq + (size_t)col * 512;
        float acc = 0.f;
        for (int k = 0; k < 512; ++k) {
            float adq = (float)ar[k] * s1;
            acc = fmaf(adq, wr[k], acc);
        }
        float tq = fmaxf(acc, 0.f) / s2;
        float code = fminf(rintf(tq), 15.f);
        A2[(size_t)row * 512 + col] = (f16)code;
    }
}

// ---------------- GEMM3: [65536,512] @ [16,512]^T -> fp32 logits ----------------

__global__ __launch_bounds__(256) void k_gemm3(
    const f16* __restrict__ A2, const f16* __restrict__ Q3,
    const float* __restrict__ wmax, const float* __restrict__ s2p,
    float* __restrict__ Out)
{
    __shared__ __align__(16) f16 As[256][72];
    __shared__ __align__(16) f16 Bs[16][72];

    const int t = threadIdx.x;
    const int row0 = blockIdx.x * 256;
    const int lane = t & 63, wv = t >> 6;

    f32x4 acc[4];
    #pragma unroll
    for (int m = 0; m < 4; ++m) acc[m] = (f32x4){0.f, 0.f, 0.f, 0.f};

    for (int k0 = 0; k0 < 512; k0 += 64) {
        #pragma unroll
        for (int i = 0; i < 8; ++i) {
            int f = t + 256 * i;
            int r = f >> 3, c = f & 7;
            *reinterpret_cast<uint4*>(&As[r][c * 8]) =
                *reinterpret_cast<const uint4*>(A2 + (size_t)(row0 + r) * 512 + k0 + c * 8);
        }
        if (t < 128) {
            int r = t >> 3, c = t & 7;
            *reinterpret_cast<uint4*>(&Bs[r][c * 8]) =
                *reinterpret_cast<const uint4*>(Q3 + (size_t)r * 512 + k0 + c * 8);
        }
        __syncthreads();

        #pragma unroll
        for (int kk = 0; kk < 2; ++kk) {
            int kb = kk * 32 + (lane >> 4) * 8;
            f16x8 bf = *reinterpret_cast<const f16x8*>(&Bs[lane & 15][kb]);
            #pragma unroll
            for (int m = 0; m < 4; ++m) {
                f16x8 af = *reinterpret_cast<const f16x8*>(&As[wv * 64 + m * 16 + (lane & 15)][kb]);
                acc[m] = MFMA16(af, bf, acc[m]);
            }
        }
        __syncthreads();
    }

    double cs = (double)s2p[0] * (double)(wmax[0] / 7.0f + 1e-8f);
    #pragma unroll
    for (int m = 0; m < 4; ++m)
        #pragma unroll
        for (int j = 0; j < 4; ++j) {
            int row = row0 + wv * 64 + m * 16 + (lane >> 4) * 4 + j;
            int col = lane & 15;
            if (col < 10)
                Out[(size_t)row * 10 + col] = (float)((double)acc[m][j] * cs);
        }
}

// ---------------- launch ----------------

extern "C" void kernel_launch(void* const* d_in, const int* in_sizes, int n_in,
                              void* d_out, int out_size, void* d_ws, size_t ws_size,
                              hipStream_t stream)
{
    (void)in_sizes; (void)n_in; (void)out_size;

    const float* X  = (const float*)d_in[0];
    const float* W1 = (const float*)d_in[1];
    const float* W2 = (const float*)d_in[2];
    const float* W3 = (const float*)d_in[3];
    const float* s1 = (const float*)d_in[4];
    const float* s2 = (const float*)d_in[5];
    float* Out = (float*)d_out;

    char* ws = (char*)d_ws;
    float* maxes   = (float*)ws;
    int*   cnts    = (int*)(ws + 16);
    f16*   q1      = (f16*)(ws + 4096);                           // 802816 B
    f16*   q2      = (f16*)(ws + (size_t)(1u << 20));             // 524288 B
    f16*   q3      = (f16*)(ws + (size_t)(1u << 20) + 600000);    // 16384 B
    f16*   q1p     = (f16*)(ws + (size_t)(2u << 20));             // 1703936 B
    float* w1dq    = (float*)(ws + (size_t)(4u << 20));           // 1605632 B
    float* w2dq    = (float*)(ws + (size_t)(6u << 20));           // 1048576 B
    f16*   a1      = (f16*)(ws + (size_t)(8u << 20));             // 64 MB
    f16*   a2      = (f16*)(ws + (size_t)(72u << 20));            // 64 MB
    unsigned* fl1  = (unsigned*)(ws + (size_t)(136u << 20));      // 4 MB
    unsigned* fl2  = (unsigned*)(ws + (size_t)(140u << 20));      // 4 MB
    f16*   Xs      = (f16*)(ws + (size_t)(144u << 20));           // 218 MB (fast path)

    const bool big = ws_size >= ((size_t)356 << 20);

    k_zero<<<1, 64, 0, stream>>>(maxes, cnts);
    k_absmax<<<256, 256, 0, stream>>>(W1, 512 * 784, maxes + 0);
    k_absmax<<<256, 256, 0, stream>>>(W2, 512 * 512, maxes + 1);
    k_absmax<<<8, 256, 0, stream>>>(W3, 10 * 512, maxes + 2);
    k_quantw1p<<<(512 * 832 + 255) / 256, 256, 0, stream>>>(W1, maxes + 0, q1, w1dq, q1p);
    k_quantw<<<(512 * 512 + 255) / 256, 256, 0, stream>>>(W2, maxes + 1, q2, w2dq, 512 * 512);
    k_quantw3<<<(16 * 512 + 255) / 256, 256, 0, stream>>>(W3, maxes + 2, q3);

    if (big) {
        k_prep<<<65536, 256, 0, stream>>>(X, Xs);
        k_gemm1f<<<2048, 256, 0, stream>>>(Xs, q1p, maxes + 0, s1, a1, cnts + 0, fl1);
    } else {
        k_gemm1s<<<dim3(4, 512), 256, 0, stream>>>(X, q1, maxes + 0, s1, a1, cnts + 0, fl1);
    }
    k_fixup1<<<512, 256, 0, stream>>>(X, w1dq, s1, cnts + 0, fl1, a1);
    k_gemm2f<<<2048, 256, 0, stream>>>(a1, q2, maxes + 1, s1, s2, a2, cnts + 1, fl2);
    k_fixup2<<<512, 256, 0, stream>>>(a1, w2dq, s1, s2, cnts + 1, fl2, a2);
    k_gemm3<<<256, 256, 0, stream>>>(a2, q3, maxes + 2, s2, Out);
}